// Round 9
// baseline (1319.363 us; speedup 1.0000x reference)
//
#include <hip/hip_runtime.h>
#include <hip/hip_bf16.h>

// QLSTM: SEQ=1024, B=64, D_IN=256, D_H=256, fp32 in/out.
// Phase 1: Xp = x @ Wx + bias (f16 MFMA GEMM); epilogue emits [t][b][h][4g] f16x4.
// Phase 2: 64 WGs (1/batch), 1024 thr, 16 waves, 4/SIMD, ONE lds_barrier/step.
//   r8 result: i8 MFMA + full weight residency -> 2400 cyc/step, but matrix-pipe
//   floor is ~1170; the other ~1200 was serial tail + latency with only 2 waves/SIMD.
//   THIS ROUND: 16 waves (4/SIMD). Wave w owns h-block w*16; thread = ONE h-col,
//   ALL 4 gates: 4 N-tiles x 4 kt = 16 tiles = 64 VGPRs (still fully resident).
//   Tail per thread halves; hv publish = 1 predicated byte-store (no shuffles, no
//   k-permutation -- natural order); Xp = ONE 8B load (f16x4 of the 4 gates).
//   D-row redundancy: A is broadcast (all 16 rows = hx) => every lane's reg0 holds
//   its column's result => all 64 lanes run the gate tail with zero cross-lane ops;
//   only lanes 0-15 store. MFMA/CU unchanged (256); 4 waves/SIMD hides ds_read+tail.
//   Precision: per-column scales (s_j/127), exact i32 accum, hx i8 @127 (r8-proven:
//   absmax unchanged at 0.0039).
// r3/r7: cross-CU exchange dead (L2 RTT). r6: all Wh must cross the MFMA B-port
//   every step -> i8 halves bytes AND fits registers; fp4/fp8 rejected (rel err
//   6-25% vs i8's 0.4%).

typedef _Float16 f16;
typedef _Float16 f16x4 __attribute__((ext_vector_type(4)));
typedef _Float16 f16x8 __attribute__((ext_vector_type(8)));
typedef float f32x4 __attribute__((ext_vector_type(4)));
typedef int i32x4 __attribute__((ext_vector_type(4)));

#define SEQ 1024
#define BATCH 64
#define DIN 256
#define DH 256
#define NCOL 1024

// ---- ws layout (bytes) ----
#define WXP_OFF   0u                 // f16 [32][1024][8]            = 524288
#define WHQ_OFF   524288u            // i8 tiles [16 w][4 g][4 kt][64 lane][16] = 262144
#define SCL_OFF   786432u            // f32 [1024] per-col scale/127 = 4096
#define BIAS_OFF  790528u            // f32 [1024]                   = 4096
#define HXS8_OFF  794624u            // i8  [64][256] natural order  = 16384
#define CXS_OFF   811008u            // f32 [64][256]                = 65536
#define XP_OFF    876544u            // f16 [Tc*64][256 h][4 g]

__device__ __forceinline__ float fast_sigmoid(float x) {
  float e = __expf(-x);
  return __builtin_amdgcn_rcpf(1.0f + e);
}
__device__ __forceinline__ float fast_tanh(float x) {
  x = fminf(fmaxf(x, -15.0f), 15.0f);
  float e = __expf(2.0f * x);
  return (e - 1.0f) * __builtin_amdgcn_rcpf(e + 1.0f);
}
// LDS-only barrier: no vmcnt drain (out-stores / Xp loads ride across).
__device__ __forceinline__ void lds_barrier() {
  asm volatile("s_waitcnt lgkmcnt(0)\n\ts_barrier" ::: "memory");
}
__device__ __forceinline__ i32x4 MQ(i32x4 a, i32x4 b, i32x4 c) {
  return __builtin_amdgcn_mfma_i32_16x16x64_i8(a, b, c, 0, 0, 0);
}

// ---------------- prep A: Wxp (f16 for xproj) + bias ----------------
__global__ void qlstm_prep(const float* __restrict__ Wf, const float* __restrict__ Wi,
                           const float* __restrict__ Wg, const float* __restrict__ Wo,
                           const float* __restrict__ bf_, const float* __restrict__ bi_,
                           const float* __restrict__ bg_, const float* __restrict__ bo_,
                           f16* __restrict__ Wxp, float* __restrict__ biasp) {
  int tid = blockIdx.x * 256 + threadIdx.x;
  if (tid < 4 * 256 * 256) {
    int g = tid >> 16;
    int rem = tid & 65535;
    int k = rem >> 8, n = rem & 255;           // k < 256: x-rows only
    const float* W = (g == 0) ? Wf : (g == 1) ? Wi : (g == 2) ? Wg : Wo;
    float v = W[k * 256 + n];
    int j = (g << 8) + n;
    Wxp[((size_t)(k >> 3) * 1024 + j) * 8 + (k & 7)] = (f16)v;
  }
  if (tid < 1024) {
    int g = tid >> 8, n = tid & 255;
    const float* bb = (g == 0) ? bf_ : (g == 1) ? bi_ : (g == 2) ? bg_ : bo_;
    biasp[tid] = bb[n];
  }
}

// ---------------- prep B: per-column i8 quantization of Wh ----------------
__global__ __launch_bounds__(256) void qlstm_prepq(
    const float* __restrict__ Wf, const float* __restrict__ Wi,
    const float* __restrict__ Wg, const float* __restrict__ Wo,
    char* __restrict__ WhQ, float* __restrict__ scl) {
  int j = blockIdx.x * 256 + threadIdx.x;     // 0..1023 gate-column
  if (j >= 1024) return;
  int g = j >> 8, n = j & 255;
  const float* W = (g == 0) ? Wf : (g == 1) ? Wi : (g == 2) ? Wg : Wo;
  float mx = 0.0f;
  for (int r = 0; r < 256; ++r) mx = fmaxf(mx, fabsf(W[(256 + r) * 256 + n]));
  float s = (mx > 0.0f) ? mx * (1.0f / 127.0f) : 1.0f;
  float inv = 1.0f / s;
  int w = n >> 4, c = n & 15;
  size_t tb = (size_t)((w * 4 + g) * 4) * 1024;       // 4 kt tiles x 1024 B
  for (int r = 0; r < 256; ++r) {                     // natural k order
    float v = W[(256 + r) * 256 + n];
    int q = (int)rintf(v * inv);
    q = q > 127 ? 127 : (q < -127 ? -127 : q);
    int kt = r >> 6, kp = r & 63;
    int lane = (kp >> 4) * 16 + c, jj = kp & 15;
    WhQ[tb + (size_t)kt * 1024 + lane * 16 + jj] = (char)q;
  }
  scl[j] = s * (1.0f / 127.0f);               // final scale: s_j/127
}

// ---------------- phase 1: Xp = x @ Wx + bias  (MFMA f16) ----------------
__global__ __launch_bounds__(256) void qlstm_xproj(
    const float* __restrict__ X, const f16* __restrict__ Wxp,
    const float* __restrict__ biasp, f16* __restrict__ Xp2) {
  __shared__ f16 As[128][72];
  __shared__ f16 Bs[8 * 128 * 8];

  int tid = threadIdx.x;
  int tm = blockIdx.x, tn = blockIdx.y;
  int wave = tid >> 6, lane = tid & 63;
  int qm = (wave & 1) * 64, qn = (wave >> 1) * 64;
  int lm = lane & 15, lk = lane >> 4;

  f32x4 acc[4][4];
#pragma unroll
  for (int a = 0; a < 4; ++a)
#pragma unroll
    for (int b = 0; b < 4; ++b) acc[a][b] = (f32x4)0.0f;

  for (int k0 = 0; k0 < 256; k0 += 64) {
    {
      int r = tid >> 1, c0 = (tid & 1) * 32;
      const float4* src = (const float4*)(X + (size_t)(tm * 128 + r) * 256 + k0 + c0);
#pragma unroll
      for (int i = 0; i < 8; ++i) {
        float4 v = src[i];
        f16x4 pk = {(f16)v.x, (f16)v.y, (f16)v.z, (f16)v.w};
        *(f16x4*)&As[r][c0 + i * 4] = pk;
      }
    }
    {
#pragma unroll
      for (int it = 0; it < 4; ++it) {
        int idx = it * 256 + tid;
        int kgi = idx >> 7, n = idx & 127;
        ((uint4*)Bs)[idx] =
            *(const uint4*)(Wxp + (((size_t)(k0 >> 3) + kgi) * 1024 + tn * 128 + n) * 8);
      }
    }
    __syncthreads();
#pragma unroll
    for (int ks = 0; ks < 2; ++ks) {
      f16x8 af[4], bfr[4];
#pragma unroll
      for (int mi = 0; mi < 4; ++mi)
        af[mi] = *(const f16x8*)&As[qm + mi * 16 + lm][ks * 32 + lk * 8];
#pragma unroll
      for (int ni = 0; ni < 4; ++ni)
        bfr[ni] = *(const f16x8*)&Bs[(((ks * 4 + lk) * 128) + qn + ni * 16 + lm) * 8];
#pragma unroll
      for (int mi = 0; mi < 4; ++mi)
#pragma unroll
        for (int ni = 0; ni < 4; ++ni)
          acc[mi][ni] = __builtin_amdgcn_mfma_f32_16x16x32_f16(af[mi], bfr[ni],
                                                               acc[mi][ni], 0, 0, 0);
    }
    __syncthreads();
  }
  // Epilogue: [m][h][g] layout so the seq kernel loads one f16x4 per thread.
  int m0 = tm * 128 + qm, j0 = tn * 128 + qn;
#pragma unroll
  for (int mi = 0; mi < 4; ++mi)
#pragma unroll
    for (int ni = 0; ni < 4; ++ni) {
      int j = j0 + ni * 16 + lm;
      int gg = j >> 8, hh = j & 255;
      float bv = biasp[j];
#pragma unroll
      for (int r = 0; r < 4; ++r) {
        int m = m0 + mi * 16 + lk * 4 + r;
        Xp2[((size_t)m * 256 + hh) * 4 + gg] = (f16)(acc[mi][ni][r] + bv);
      }
    }
}

// ---------------- phase 2: sequential LSTM, i8 MFMA, 16 waves ----------------
__global__ __launch_bounds__(1024, 4) void qlstm_seq(
    const f16* __restrict__ Xp2, const i32x4* __restrict__ WhQ,
    const float* __restrict__ scl,
    float* __restrict__ out, char* __restrict__ hxs8, float* __restrict__ cxs,
    float* __restrict__ hxout, float* __restrict__ cxout, int t0, int t1) {
  __shared__ char hxq[2][256];                 // i8 hidden state, natural order

  int tid = threadIdx.x;
  int wv = tid >> 6, lane = tid & 63, c = lane & 15;
  int b = blockIdx.x;
  int h = wv * 16 + c;                         // my h column (all 4 gates)

  // weights: 4 gates x 4 kt tiles, 16B/lane = 64 VGPRs (fully resident)
  i32x4 wq[4][4];
  {
    const i32x4* wp = WhQ + (size_t)(wv * 16) * 64 + lane;
#pragma unroll
    for (int g = 0; g < 4; ++g)
#pragma unroll
      for (int kt = 0; kt < 4; ++kt) wq[g][kt] = wp[(g * 4 + kt) * 64];
  }
  float sc[4];
#pragma unroll
  for (int g = 0; g < 4; ++g) sc[g] = scl[g * 256 + h];

  int par0 = t0 & 1;
  if (tid < 16) {
    uint4 v;
    if (t0 == 0) v = uint4{0u, 0u, 0u, 0u};
    else v = ((const uint4*)(hxs8 + (size_t)b * 256))[tid];
    *(uint4*)(&hxq[par0][tid * 16]) = v;
  }
  float cx = (t0 != 0) ? cxs[(size_t)b * 256 + h] : 0.0f;

  __syncthreads();

  int koff = (lane >> 4) << 4;                 // A-frag k-chunk byte offset
  float hv = 0.0f;
  for (int t = t0; t < t1; ++t) {
    int par = t & 1, parn = par ^ 1;
    const char* hp = &hxq[par][0];

    // Xp: ONE 8B load = f16x4 of my 4 gate pre-projections (rides vmcnt)
    uint2 xr = *(const uint2*)(Xp2 + (((size_t)(t - t0) * BATCH + b) * 256 + h) * 4);

    // 4 K-tiles x 4 N-tiles i8 MFMA; A pipelined one ahead
    i32x4 acc0{}, acc1{}, acc2{}, acc3{};
    i32x4 a0 = *(const i32x4*)(hp + koff);
    i32x4 a1 = *(const i32x4*)(hp + 64 + koff);
    acc0 = MQ(a0, wq[0][0], acc0); acc1 = MQ(a0, wq[1][0], acc1);
    acc2 = MQ(a0, wq[2][0], acc2); acc3 = MQ(a0, wq[3][0], acc3);
    a0 = *(const i32x4*)(hp + 128 + koff);
    acc0 = MQ(a1, wq[0][1], acc0); acc1 = MQ(a1, wq[1][1], acc1);
    acc2 = MQ(a1, wq[2][1], acc2); acc3 = MQ(a1, wq[3][1], acc3);
    a1 = *(const i32x4*)(hp + 192 + koff);
    acc0 = MQ(a0, wq[0][2], acc0); acc1 = MQ(a0, wq[1][2], acc1);
    acc2 = MQ(a0, wq[2][2], acc2); acc3 = MQ(a0, wq[3][2], acc3);
    acc0 = MQ(a1, wq[0][3], acc0); acc1 = MQ(a1, wq[1][3], acc1);
    acc2 = MQ(a1, wq[2][3], acc2); acc3 = MQ(a1, wq[3][3], acc3);

    // A is broadcast => every lane's reg0 = its column's dot; dequant + x-proj
    f16x4 xh = __builtin_bit_cast(f16x4, xr);
    float p0 = fmaf((float)acc0[0], sc[0], (float)xh[0]);
    float p1 = fmaf((float)acc1[0], sc[1], (float)xh[1]);
    float p2 = fmaf((float)acc2[0], sc[2], (float)xh[2]);
    float p3 = fmaf((float)acc3[0], sc[3], (float)xh[3]);

    float vf = fast_sigmoid(p0);
    float vi = fast_sigmoid(p1);
    float vg = fast_tanh(p2);
    float vo = fast_sigmoid(p3);
    cx = fmaf(vf, cx, vi * vg);
    hv = vo * fast_tanh(cx);

    if (lane < 16) {
      out[((size_t)t * BATCH + b) * 256 + h] = hv;      // rides vmcnt
      hxq[parn][h] = (char)(int)rintf(hv * 127.0f);     // |hv|<1 => in range
    }
    lds_barrier();                             // lgkmcnt(0)+s_barrier only
  }

  // persist state across chunk launches (exact i8 state + f32 cx)
  if (tid < 16)
    ((uint4*)(hxs8 + (size_t)b * 256))[tid] = *(const uint4*)(&hxq[t1 & 1][tid * 16]);
  if (lane < 16) {
    cxs[(size_t)b * 256 + h] = cx;
    if (t1 == SEQ) {
      hxout[(size_t)b * 256 + h] = hv;
      cxout[(size_t)b * 256 + h] = cx;
    }
  }
}

extern "C" void kernel_launch(void* const* d_in, const int* in_sizes, int n_in,
                              void* d_out, int out_size, void* d_ws, size_t ws_size,
                              hipStream_t stream) {
  const float* X  = (const float*)d_in[0];
  const float* Wf = (const float*)d_in[1]; const float* bf_ = (const float*)d_in[2];
  const float* Wi = (const float*)d_in[3]; const float* bi_ = (const float*)d_in[4];
  const float* Wg = (const float*)d_in[5]; const float* bg_ = (const float*)d_in[6];
  const float* Wo = (const float*)d_in[7]; const float* bo_ = (const float*)d_in[8];
  float* out = (float*)d_out;

  char* ws = (char*)d_ws;
  f16*   Wxp   = (f16*)(ws + WXP_OFF);
  char*  WhQ   = (char*)(ws + WHQ_OFF);
  float* scl   = (float*)(ws + SCL_OFF);
  float* biasp = (float*)(ws + BIAS_OFF);
  char*  hxs8  = (char*)(ws + HXS8_OFF);
  float* cxs   = (float*)(ws + CXS_OFF);
  f16*   Xp2   = (f16*)(ws + XP_OFF);

  size_t avail = (ws_size > XP_OFF) ? (ws_size - XP_OFF) : 0;
  int Tc = SEQ;
  while (Tc > 2 && (size_t)Tc * BATCH * NCOL * 2 > avail) Tc >>= 1;

  qlstm_prep<<<1024, 256, 0, stream>>>(Wf, Wi, Wg, Wo, bf_, bi_, bg_, bo_,
                                       Wxp, biasp);
  qlstm_prepq<<<4, 256, 0, stream>>>(Wf, Wi, Wg, Wo, WhQ, scl);

  float* hxout = out + (size_t)SEQ * BATCH * DH;
  float* cxout = hxout + BATCH * DH;

  for (int t0 = 0; t0 < SEQ; t0 += Tc) {
    dim3 g1(Tc * BATCH / 128, NCOL / 128);
    qlstm_xproj<<<g1, 256, 0, stream>>>(X + (size_t)t0 * BATCH * DIN, Wxp, biasp, Xp2);
    qlstm_seq<<<BATCH, 1024, 0, stream>>>(Xp2, (const i32x4*)WhQ, scl, out, hxs8, cxs,
                                          hxout, cxout, t0, t0 + Tc);
  }
}

// Round 10
// 1161.420 us; speedup vs baseline: 1.1360x; 1.1360x over previous
//
#include <hip/hip_runtime.h>
#include <hip/hip_bf16.h>

// QLSTM: SEQ=1024, B=64, D_IN=256, D_H=256, fp32 in/out.
// Phase 1: Xp = x @ Wx + bias (f16 MFMA GEMM); COLUMN-PERMUTED j' = h*4+g so the
//   epilogue stores are contiguous f16 runs (was scattered 2B @ stride 8B) and the
//   seq kernel reads one 8B f16x4 per (b,h).
// Phase 2 (r9-proven shell): 64 WGs (1/batch), 1024 thr, 16 waves, 4/SIMD, i8 MFMA,
//   weights fully register-resident (AGPR-backed is fine: MFMA reads AGPR natively),
//   ONE lds_barrier/step. r10: all 4 A-frags ds_read upfront (no mid-phase lgkm
//   stalls); hv LDS write ordered before the out global store.
// Cycle model (r9 measured 2217 cyc/step): i8 B-port floor 1305 + lockstep DS burst
//   ~300 + tail burst ~350 + barrier skew. Stagger escapes are register-infeasible
//   (2 batches/WG staggered needs 2x weight regs/wave; M-batching leaves the per-CU
//   B-stream invariant). Remaining cheap time is OUTSIDE seq: xproj + prepq.
// prepq split: atomicMax colmax pass (coalesced, 32 WGs) + parallel quant (1024 WGs).
// r3/r7: cross-CU exchange dead. r6: all Wh crosses the MFMA B-port every step.
// r8: per-column i8 scales + i32 accum + hx@127 leave absmax unchanged (0.0039).

typedef _Float16 f16;
typedef _Float16 f16x4 __attribute__((ext_vector_type(4)));
typedef _Float16 f16x8 __attribute__((ext_vector_type(8)));
typedef float f32x4 __attribute__((ext_vector_type(4)));
typedef int i32x4 __attribute__((ext_vector_type(4)));

#define SEQ 1024
#define BATCH 64
#define DIN 256
#define DH 256
#define NCOL 1024

// ---- ws layout (bytes) ----
#define WXP_OFF   0u                 // f16 [32][1024][8], cols j'=h*4+g  = 524288
#define WHQ_OFF   524288u            // i8 tiles [16 w][4 g][4 kt][64][16] = 262144
#define SCL_OFF   786432u            // f32 [1024] final scale (s_j/127)
#define BIAS_OFF  790528u            // f32 [1024], j'-indexed
#define HXS8_OFF  794624u            // i8  [64][256]
#define CXS_OFF   811008u            // f32 [64][256]
#define SMX_OFF   876544u            // int [1024] colmax bits (atomicMax scratch)
#define XP_OFF    880640u            // f16 [Tc*64][256 h][4 g]

__device__ __forceinline__ float fast_sigmoid(float x) {
  float e = __expf(-x);
  return __builtin_amdgcn_rcpf(1.0f + e);
}
__device__ __forceinline__ float fast_tanh(float x) {
  x = fminf(fmaxf(x, -15.0f), 15.0f);
  float e = __expf(2.0f * x);
  return (e - 1.0f) * __builtin_amdgcn_rcpf(e + 1.0f);
}
// LDS-only barrier: no vmcnt drain (out-stores / Xp loads ride across).
__device__ __forceinline__ void lds_barrier() {
  asm volatile("s_waitcnt lgkmcnt(0)\n\ts_barrier" ::: "memory");
}
__device__ __forceinline__ i32x4 MQ(i32x4 a, i32x4 b, i32x4 c) {
  return __builtin_amdgcn_mfma_i32_16x16x64_i8(a, b, c, 0, 0, 0);
}

// ---------------- prep A: Wxp (f16, permuted cols) + bias + smx zero ----------------
__global__ void qlstm_prep(const float* __restrict__ Wf, const float* __restrict__ Wi,
                           const float* __restrict__ Wg, const float* __restrict__ Wo,
                           const float* __restrict__ bf_, const float* __restrict__ bi_,
                           const float* __restrict__ bg_, const float* __restrict__ bo_,
                           f16* __restrict__ Wxp, float* __restrict__ biasp,
                           int* __restrict__ smx) {
  int tid = blockIdx.x * 256 + threadIdx.x;
  if (tid < 4 * 256 * 256) {
    int g = tid >> 16;
    int rem = tid & 65535;
    int k = rem >> 8, n = rem & 255;           // k < 256: x-rows only
    const float* W = (g == 0) ? Wf : (g == 1) ? Wi : (g == 2) ? Wg : Wo;
    float v = W[k * 256 + n];
    int j = n * 4 + g;                         // PERMUTED column
    Wxp[((size_t)(k >> 3) * 1024 + j) * 8 + (k & 7)] = (f16)v;
  }
  if (tid < 1024) {
    int g = tid >> 8, n = tid & 255;
    const float* bb = (g == 0) ? bf_ : (g == 1) ? bi_ : (g == 2) ? bg_ : bo_;
    biasp[n * 4 + g] = bb[n];                  // PERMUTED bias
    smx[tid] = 0;                              // colmax scratch (re-zeroed per replay)
  }
}

// ---------------- prep B1: per-column |max| via atomicMax (coalesced) ----------------
__global__ __launch_bounds__(256) void qlstm_prepmax(
    const float* __restrict__ Wf, const float* __restrict__ Wi,
    const float* __restrict__ Wg, const float* __restrict__ Wo,
    int* __restrict__ smx) {
  int bk = blockIdx.x;                // 32 blocks: g = bk&3, row-chunk = bk>>2
  int g = bk & 3, r0 = (bk >> 2) * 32;
  int n = threadIdx.x;                // coalesced across n
  const float* W = (g == 0) ? Wf : (g == 1) ? Wi : (g == 2) ? Wg : Wo;
  float pm = 0.0f;
  for (int r = 0; r < 32; ++r)
    pm = fmaxf(pm, fabsf(W[(size_t)(256 + r0 + r) * 256 + n]));
  atomicMax(&smx[g * 256 + n], __float_as_int(pm));   // >=0 -> int order == float
}

// ---------------- prep B2: quantize Wh (fully parallel, coalesced reads) ----------------
__global__ __launch_bounds__(256) void qlstm_prepq(
    const float* __restrict__ Wf, const float* __restrict__ Wi,
    const float* __restrict__ Wg, const float* __restrict__ Wo,
    const int* __restrict__ smx, char* __restrict__ WhQ, float* __restrict__ scl) {
  int bk = blockIdx.x;                // 1024 blocks: g = bk&3, r = bk>>2
  int g = bk & 3, r = bk >> 2;
  int n = threadIdx.x;
  const float* W = (g == 0) ? Wf : (g == 1) ? Wi : (g == 2) ? Wg : Wo;
  float mx = __int_as_float(smx[g * 256 + n]);
  float s = (mx > 0.0f) ? mx * (1.0f / 127.0f) : 1.0f;
  float v = W[(size_t)(256 + r) * 256 + n];
  int q = (int)rintf(v * (1.0f / s));
  q = q > 127 ? 127 : (q < -127 ? -127 : q);
  int w = n >> 4, c = n & 15;
  int kt = r >> 6, kp = r & 63;
  int lane = (kp >> 4) * 16 + c, jj = kp & 15;
  WhQ[((size_t)((w * 16 + g * 4 + kt) * 64 + lane)) * 16 + jj] = (char)q;
  if (r == 0) scl[g * 256 + n] = s * (1.0f / 127.0f);
}

// ---------------- phase 1: Xp = x @ Wx + bias  (MFMA f16) ----------------
__global__ __launch_bounds__(256) void qlstm_xproj(
    const float* __restrict__ X, const f16* __restrict__ Wxp,
    const float* __restrict__ biasp, f16* __restrict__ Xp2) {
  __shared__ f16 As[128][72];
  __shared__ f16 Bs[8 * 128 * 8];

  int tid = threadIdx.x;
  int tm = blockIdx.x, tn = blockIdx.y;
  int wave = tid >> 6, lane = tid & 63;
  int qm = (wave & 1) * 64, qn = (wave >> 1) * 64;
  int lm = lane & 15, lk = lane >> 4;

  f32x4 acc[4][4];
#pragma unroll
  for (int a = 0; a < 4; ++a)
#pragma unroll
    for (int b = 0; b < 4; ++b) acc[a][b] = (f32x4)0.0f;

  for (int k0 = 0; k0 < 256; k0 += 64) {
    {
      int r = tid >> 1, c0 = (tid & 1) * 32;
      const float4* src = (const float4*)(X + (size_t)(tm * 128 + r) * 256 + k0 + c0);
#pragma unroll
      for (int i = 0; i < 8; ++i) {
        float4 v = src[i];
        f16x4 pk = {(f16)v.x, (f16)v.y, (f16)v.z, (f16)v.w};
        *(f16x4*)&As[r][c0 + i * 4] = pk;
      }
    }
    {
#pragma unroll
      for (int it = 0; it < 4; ++it) {
        int idx = it * 256 + tid;
        int kgi = idx >> 7, n = idx & 127;
        ((uint4*)Bs)[idx] =
            *(const uint4*)(Wxp + (((size_t)(k0 >> 3) + kgi) * 1024 + tn * 128 + n) * 8);
      }
    }
    __syncthreads();
#pragma unroll
    for (int ks = 0; ks < 2; ++ks) {
      f16x8 af[4], bfr[4];
#pragma unroll
      for (int mi = 0; mi < 4; ++mi)
        af[mi] = *(const f16x8*)&As[qm + mi * 16 + lm][ks * 32 + lk * 8];
#pragma unroll
      for (int ni = 0; ni < 4; ++ni)
        bfr[ni] = *(const f16x8*)&Bs[(((ks * 4 + lk) * 128) + qn + ni * 16 + lm) * 8];
#pragma unroll
      for (int mi = 0; mi < 4; ++mi)
#pragma unroll
        for (int ni = 0; ni < 4; ++ni)
          acc[mi][ni] = __builtin_amdgcn_mfma_f32_16x16x32_f16(af[mi], bfr[ni],
                                                               acc[mi][ni], 0, 0, 0);
    }
    __syncthreads();
  }
  // Epilogue: j is j' = h*4+g -> stores are CONTIGUOUS f16 runs per 16 lanes.
  int m0 = tm * 128 + qm, j0 = tn * 128 + qn;
#pragma unroll
  for (int mi = 0; mi < 4; ++mi)
#pragma unroll
    for (int ni = 0; ni < 4; ++ni) {
      int j = j0 + ni * 16 + lm;
      float bv = biasp[j];
#pragma unroll
      for (int r = 0; r < 4; ++r) {
        int m = m0 + mi * 16 + lk * 4 + r;
        Xp2[(size_t)m * 1024 + j] = (f16)(acc[mi][ni][r] + bv);
      }
    }
}

// ---------------- phase 2: sequential LSTM, i8 MFMA, 16 waves ----------------
__global__ __launch_bounds__(1024, 4) void qlstm_seq(
    const f16* __restrict__ Xp2, const i32x4* __restrict__ WhQ,
    const float* __restrict__ scl,
    float* __restrict__ out, char* __restrict__ hxs8, float* __restrict__ cxs,
    float* __restrict__ hxout, float* __restrict__ cxout, int t0, int t1) {
  __shared__ char hxq[2][256];                 // i8 hidden state, natural order

  int tid = threadIdx.x;
  int wv = tid >> 6, lane = tid & 63, c = lane & 15;
  int b = blockIdx.x;
  int h = wv * 16 + c;                         // my h column (all 4 gates)

  // weights: 4 gates x 4 kt tiles, 16B/lane = 64 regs (VGPR/AGPR; MFMA reads both)
  i32x4 wq[4][4];
  {
    const i32x4* wp = WhQ + (size_t)(wv * 16) * 64 + lane;
#pragma unroll
    for (int g = 0; g < 4; ++g)
#pragma unroll
      for (int kt = 0; kt < 4; ++kt) wq[g][kt] = wp[(g * 4 + kt) * 64];
  }
  float sc[4];
#pragma unroll
  for (int g = 0; g < 4; ++g) sc[g] = scl[g * 256 + h];

  int par0 = t0 & 1;
  if (tid < 16) {
    uint4 v;
    if (t0 == 0) v = uint4{0u, 0u, 0u, 0u};
    else v = ((const uint4*)(hxs8 + (size_t)b * 256))[tid];
    *(uint4*)(&hxq[par0][tid * 16]) = v;
  }
  float cx = (t0 != 0) ? cxs[(size_t)b * 256 + h] : 0.0f;

  __syncthreads();

  int koff = (lane >> 4) << 4;                 // A-frag k-chunk byte offset
  float hv = 0.0f;
  for (int t = t0; t < t1; ++t) {
    int par = t & 1, parn = par ^ 1;
    const char* hp = &hxq[par][0];

    // Xp: ONE 8B load = f16x4 of my 4 gate pre-projections (rides vmcnt)
    uint2 xr = *(const uint2*)(Xp2 + (((size_t)(t - t0) * BATCH + b) * 256 + h) * 4);

    // all 4 A-frags upfront: no mid-MFMA-phase lgkmcnt stalls
    i32x4 a0 = *(const i32x4*)(hp + koff);
    i32x4 a1 = *(const i32x4*)(hp + 64 + koff);
    i32x4 a2 = *(const i32x4*)(hp + 128 + koff);
    i32x4 a3 = *(const i32x4*)(hp + 192 + koff);

    i32x4 acc0{}, acc1{}, acc2{}, acc3{};
    acc0 = MQ(a0, wq[0][0], acc0); acc1 = MQ(a0, wq[1][0], acc1);
    acc2 = MQ(a0, wq[2][0], acc2); acc3 = MQ(a0, wq[3][0], acc3);
    acc0 = MQ(a1, wq[0][1], acc0); acc1 = MQ(a1, wq[1][1], acc1);
    acc2 = MQ(a1, wq[2][1], acc2); acc3 = MQ(a1, wq[3][1], acc3);
    acc0 = MQ(a2, wq[0][2], acc0); acc1 = MQ(a2, wq[1][2], acc1);
    acc2 = MQ(a2, wq[2][2], acc2); acc3 = MQ(a2, wq[3][2], acc3);
    acc0 = MQ(a3, wq[0][3], acc0); acc1 = MQ(a3, wq[1][3], acc1);
    acc2 = MQ(a3, wq[2][3], acc2); acc3 = MQ(a3, wq[3][3], acc3);

    // A broadcast => every lane's reg0 = its column's dot; dequant + x-proj
    f16x4 xh = __builtin_bit_cast(f16x4, xr);
    float p0 = fmaf((float)acc0[0], sc[0], (float)xh[0]);
    float p1 = fmaf((float)acc1[0], sc[1], (float)xh[1]);
    float p2 = fmaf((float)acc2[0], sc[2], (float)xh[2]);
    float p3 = fmaf((float)acc3[0], sc[3], (float)xh[3]);

    float vf = fast_sigmoid(p0);
    float vi = fast_sigmoid(p1);
    float vg = fast_tanh(p2);
    float vo = fast_sigmoid(p3);
    cx = fmaf(vf, cx, vi * vg);
    hv = vo * fast_tanh(cx);

    if (lane < 16) {
      hxq[parn][h] = (char)(int)rintf(hv * 127.0f);     // LDS write first
      out[((size_t)t * BATCH + b) * 256 + h] = hv;      // rides vmcnt
    }
    lds_barrier();                             // lgkmcnt(0)+s_barrier only
  }

  // persist state across chunk launches (exact i8 state + f32 cx)
  if (tid < 16)
    ((uint4*)(hxs8 + (size_t)b * 256))[tid] = *(const uint4*)(&hxq[t1 & 1][tid * 16]);
  if (lane < 16) {
    cxs[(size_t)b * 256 + h] = cx;
    if (t1 == SEQ) {
      hxout[(size_t)b * 256 + h] = hv;
      cxout[(size_t)b * 256 + h] = cx;
    }
  }
}

extern "C" void kernel_launch(void* const* d_in, const int* in_sizes, int n_in,
                              void* d_out, int out_size, void* d_ws, size_t ws_size,
                              hipStream_t stream) {
  const float* X  = (const float*)d_in[0];
  const float* Wf = (const float*)d_in[1]; const float* bf_ = (const float*)d_in[2];
  const float* Wi = (const float*)d_in[3]; const float* bi_ = (const float*)d_in[4];
  const float* Wg = (const float*)d_in[5]; const float* bg_ = (const float*)d_in[6];
  const float* Wo = (const float*)d_in[7]; const float* bo_ = (const float*)d_in[8];
  float* out = (float*)d_out;

  char* ws = (char*)d_ws;
  f16*   Wxp   = (f16*)(ws + WXP_OFF);
  char*  WhQ   = (char*)(ws + WHQ_OFF);
  float* scl   = (float*)(ws + SCL_OFF);
  float* biasp = (float*)(ws + BIAS_OFF);
  char*  hxs8  = (char*)(ws + HXS8_OFF);
  float* cxs   = (float*)(ws + CXS_OFF);
  int*   smx   = (int*)(ws + SMX_OFF);
  f16*   Xp2   = (f16*)(ws + XP_OFF);

  size_t avail = (ws_size > XP_OFF) ? (ws_size - XP_OFF) : 0;
  int Tc = SEQ;
  while (Tc > 2 && (size_t)Tc * BATCH * NCOL * 2 > avail) Tc >>= 1;

  qlstm_prep<<<1024, 256, 0, stream>>>(Wf, Wi, Wg, Wo, bf_, bi_, bg_, bo_,
                                       Wxp, biasp, smx);
  qlstm_prepmax<<<32, 256, 0, stream>>>(Wf, Wi, Wg, Wo, smx);
  qlstm_prepq<<<1024, 256, 0, stream>>>(Wf, Wi, Wg, Wo, smx, WhQ, scl);

  float* hxout = out + (size_t)SEQ * BATCH * DH;
  float* cxout = hxout + BATCH * DH;

  for (int t0 = 0; t0 < SEQ; t0 += Tc) {
    dim3 g1(Tc * BATCH / 128, NCOL / 128);
    qlstm_xproj<<<g1, 256, 0, stream>>>(X + (size_t)t0 * BATCH * DIN, Wxp, biasp, Xp2);
    qlstm_seq<<<BATCH, 1024, 0, stream>>>(Xp2, (const i32x4*)WhQ, scl, out, hxs8, cxs,
                                          hxout, cxout, t0, t0 + Tc);
  }
}